// Round 1
// baseline (14421.735 us; speedup 1.0000x reference)
//
#include <hip/hip_runtime.h>
#include <hip/hip_fp16.h>

#define TSEQ 1024
#define NBATCH 256
#define HD 256
#define ID 128
#define ODIM 128
#define NGRP 8
#define TILES 2

typedef _Float16 f16;
typedef _Float16 f16x8 __attribute__((ext_vector_type(8)));
typedef float f32x4 __attribute__((ext_vector_type(4)));
typedef unsigned int u32;
typedef unsigned long long u64;

// ---------------------------------------------------------------------------
// K0: pack recurrent + input weights into fp16, row order n' = j*256 + g*64 + uu
// (unchanged from previous version)
// ---------------------------------------------------------------------------
__global__ void pack_weights(
    const float* __restrict__ Wgh, const float* __restrict__ Wih,
    const float* __restrict__ Wfh, const float* __restrict__ Woh,
    const float* __restrict__ Wgx, const float* __restrict__ Wix,
    const float* __restrict__ Wfx, const float* __restrict__ Wox,
    const float* __restrict__ bgx, const float* __restrict__ bix,
    const float* __restrict__ bfx, const float* __restrict__ box,
    f16* __restrict__ Whcat, f16* __restrict__ Wxcat, float* __restrict__ bcat)
{
    const int np = blockIdx.x;            // 0..1023  (row n')
    const int g  = (np >> 6) & 3;         // gate
    const int j  = np >> 8;               // hidden slice
    const int uu = np & 63;
    const int u  = j * 64 + uu;           // global hidden unit
    const float* Wh = (g == 0) ? Wgh : (g == 1) ? Wih : (g == 2) ? Wfh : Woh;
    const float* Wx = (g == 0) ? Wgx : (g == 1) ? Wix : (g == 2) ? Wfx : Wox;
    const float* bx = (g == 0) ? bgx : (g == 1) ? bix : (g == 2) ? bfx : box;
    const int k = threadIdx.x;            // 0..255
    Whcat[np * 256 + k] = (f16)Wh[u * 256 + k];
    if (k < ID) Wxcat[np * ID + k] = (f16)Wx[u * ID + k];
    if (k == 0) bcat[np] = bx[u];
}

// ---------------------------------------------------------------------------
// K2: persistent fused recurrence, tagged-h dataflow protocol.
//
// 32 WGs x 256 threads. WG = (grp 0..7, j 0..3). Group grp owns batches
// [grp*32, grp*32+32) as TWO independent 16-batch tiles (independent
// recurrence chains) that are processed in alternating phases — tile1's
// compute hides tile0's exchange latency and vice versa.
//
// h exchange: each h value is published as a u32 atom  (t<<16) | fp16(h)
// with a RELAXED agent-scope store. Consumers load tagged u64 pairs and
// validate tag==t-1 per dword; the tag travels WITH the payload so no
// fences, no vmcnt drains, no flags, no polls, no __syncthreads anywhere.
// Parity double-buffer (t&1) prevents too-new overwrites: a producer needs
// every peer's h(t) before it can store h(t+1), so it can never be 2 steps
// ahead of a reader. hbt is memset to 0xFF each launch (tag 0xFFFF never
// matches), killing cross-launch stale-tag races.
//
// MFMA 16x16x32 f16 layouts:
//   A[m = lane&15][k = (lane>>4)*8 + e]
//   B[n = lane&15][k = (lane>>4)*8 + e]
//   D[m = (lane>>4)*4 + r][n = lane&15]
// ---------------------------------------------------------------------------

__device__ __forceinline__ void load_xrow(const float* xp, int q, float4 (&xr)[8])
{
#pragma unroll
    for (int k4 = 0; k4 < 4; ++k4) {
        xr[k4 * 2]     = *(const float4*)&xp[k4 * 32 + q * 8];
        xr[k4 * 2 + 1] = *(const float4*)&xp[k4 * 32 + q * 8 + 4];
    }
}

__device__ __forceinline__ void conv_xa(const float4 (&xr)[8], f16x8 (&xa)[4])
{
#pragma unroll
    for (int k4 = 0; k4 < 4; ++k4) {
        const float* f0 = (const float*)&xr[k4 * 2];
        const float* f1 = (const float*)&xr[k4 * 2 + 1];
#pragma unroll
        for (int e = 0; e < 4; ++e) {
            xa[k4][e]     = (f16)f0[e];
            xa[k4][4 + e] = (f16)f1[e];
        }
    }
}

__global__ __launch_bounds__(256, 1) void lstm_rec(
    const float* __restrict__ x,
    const f16* __restrict__ Whcat,
    const f16* __restrict__ Wxcat,
    const float* __restrict__ bcat,
    u32* __restrict__ hbt,      // [NGRP][TILES][2 parity][16 b][HD] tagged h
    float* __restrict__ hT)     // [NBATCH][HD] fp32 final h
{
    const int tid  = threadIdx.x;
    const int lane = tid & 63;
    const int w    = tid >> 6;      // wave 0..3 -> units [w*16, w*16+16)
    const int q    = lane >> 4;
    const int n    = lane & 15;
    const int bid  = blockIdx.x;
    const int grp  = bid >> 2;      // 0..7
    const int j    = bid & 3;

    // ---- persistent weight fragments ----
    f16x8 wh[4][8];   // [gate][kk] recurrent, K=256 -> 8 MFMA k-steps
    f16x8 wx[4][4];   // [gate][k4] input,     K=128 -> 4 MFMA k-steps
    float bias[4];
#pragma unroll
    for (int g = 0; g < 4; ++g) {
        const int row = j * 256 + g * 64 + w * 16 + n;
        bias[g] = bcat[row];
#pragma unroll
        for (int kk = 0; kk < 8; ++kk)
            wh[g][kk] = *(const f16x8*)&Whcat[row * 256 + kk * 32 + q * 8];
#pragma unroll
        for (int k4 = 0; k4 < 4; ++k4)
            wx[g][k4] = *(const f16x8*)&Wxcat[row * ID + k4 * 32 + q * 8];
    }

    const int uglob = j * 64 + w * 16 + n;
    u32* gbase = hbt + (size_t)grp * (TILES * 2 * 16 * HD);
    const float* xrow0 = &x[(size_t)(grp * 32 + n) * TSEQ * ID];
    const float* xrow1 = &x[(size_t)(grp * 32 + 16 + n) * TSEQ * ID];

    float4 xr0[8], xr1[8];              // per-tile x(t) buffers, 2-phase-deep prefetch
    load_xrow(xrow0, q, xr0);           // x(0), tile 0
    load_xrow(xrow1, q, xr1);           // x(0), tile 1

    float c0[4] = {0.f, 0.f, 0.f, 0.f};
    float c1[4] = {0.f, 0.f, 0.f, 0.f};
    u64 hv[32];                         // tagged h for the CURRENT phase (8 kk x 4 u64)

    // ---- t = 0 prologue: x-projection only, c starts at 0 ----
    auto prologue = [&](int k, const float* xrow, float4 (&xr)[8], float (&c)[4]) {
        f16x8 xa[4];
        conv_xa(xr, xa);
        load_xrow(xrow + ID, q, xr);    // prefetch x(1)
        f32x4 acc[4];
#pragma unroll
        for (int g = 0; g < 4; ++g) { f32x4 a = {bias[g], bias[g], bias[g], bias[g]}; acc[g] = a; }
#pragma unroll
        for (int k4 = 0; k4 < 4; ++k4)
#pragma unroll
            for (int g = 0; g < 4; ++g)
                acc[g] = __builtin_amdgcn_mfma_f32_16x16x32_f16(xa[k4], wx[g][k4], acc[g], 0, 0, 0);
        u32* sp = gbase + (size_t)((k * 2 + 0) * 16 + q * 4) * HD + uglob;   // parity 0, tag 0
#pragma unroll
        for (int r = 0; r < 4; ++r) {
            const float gp_ = acc[0][r], ip_ = acc[1][r], op_ = acc[3][r];
            const float gg = 1.f - 2.f / (1.f + __expf(2.f * gp_));
            const float ii = 1.f / (1.f + __expf(-ip_));
            const float oo = 1.f / (1.f + __expf(-op_));
            c[r] = gg * ii;
            const float hh = (1.f - 2.f / (1.f + __expf(2.f * c[r]))) * oo;
            union { _Float16 f; unsigned short s; } cv;
            cv.f = (_Float16)hh;
            __hip_atomic_store(sp + r * HD, (u32)cv.s, __ATOMIC_RELAXED, __HIP_MEMORY_SCOPE_AGENT);
        }
    };
    prologue(0, xrow0, xr0, c0);
    prologue(1, xrow1, xr1, c1);

    // ---- initial tagged-h issue for (t=1, tile 0): parity 0, expect tag 0 ----
    {
        const u64* hp = (const u64*)(gbase + (size_t)(0 * 16 + n) * HD) + q * 4;
#pragma unroll
        for (int kk = 0; kk < 8; ++kk)
#pragma unroll
            for (int m = 0; m < 4; ++m)
                hv[kk * 4 + m] = __hip_atomic_load(hp + kk * 16 + m, __ATOMIC_RELAXED,
                                                   __HIP_MEMORY_SCOPE_AGENT);
    }

    // ---- main loop: phases alternate tile 0 / tile 1 ----
    auto phase = [&](int t, int k, const float* xrow, float4 (&xr)[8], float (&c)[4]) {
        // 1. convert x(t) then prefetch x(t+1) into the same buffer (2-phase depth)
        f16x8 xa[4];
        conv_xa(xr, xa);
        const int tt = (t + 1 < TSEQ) ? t + 1 : TSEQ - 1;   // clamp: avoid OOB, value unused at end
        load_xrow(xrow + (size_t)tt * ID, q, xr);

        // 2. x-projection MFMAs (independent of h)
        f32x4 acc[4];
#pragma unroll
        for (int g = 0; g < 4; ++g) { f32x4 a = {bias[g], bias[g], bias[g], bias[g]}; acc[g] = a; }
#pragma unroll
        for (int k4 = 0; k4 < 4; ++k4)
#pragma unroll
            for (int g = 0; g < 4; ++g)
                acc[g] = __builtin_amdgcn_mfma_f32_16x16x32_f16(xa[k4], wx[g][k4], acc[g], 0, 0, 0);

        // 3. validate tagged h(t-1) for this tile (loads were issued last phase)
        const int pp = (t - 1) & 1;
        const u64* hp = (const u64*)(gbase + (size_t)((k * 2 + pp) * 16 + n) * HD) + q * 4;
        const u64 pat = (u64)(t - 1) * 0x0001000000010000ULL;   // tag<<16 | tag<<48
        for (;;) {
            u64 diff = 0;
#pragma unroll
            for (int i = 0; i < 32; ++i) diff |= hv[i] ^ pat;
            if ((diff & 0xFFFF0000FFFF0000ULL) == 0ULL) break;
#pragma unroll
            for (int kk = 0; kk < 8; ++kk)
#pragma unroll
                for (int m = 0; m < 4; ++m)
                    hv[kk * 4 + m] = __hip_atomic_load(hp + kk * 16 + m, __ATOMIC_RELAXED,
                                                       __HIP_MEMORY_SCOPE_AGENT);
        }

        // 4. recurrent MFMAs with inline extract; interleave next-phase tagged-h issue
        //    next phase: k==0 -> (t, tile1): tag t-1, parity (t-1)&1
        //                k==1 -> (t+1, tile0): tag t,  parity t&1
        //    (at (1023,1) this loads a harmless never-checked slot — always in bounds)
        const int kn = k ^ 1;
        const int pn = (k == 0) ? pp : (t & 1);
        const u64* hpn = (const u64*)(gbase + (size_t)((kn * 2 + pn) * 16 + n) * HD) + q * 4;
#pragma unroll
        for (int kk = 0; kk < 8; ++kk) {
            union { unsigned short us[8]; f16x8 v; } hu;
#pragma unroll
            for (int e2 = 0; e2 < 4; ++e2) {
                const u64 d = hv[kk * 4 + e2];
                hu.us[e2 * 2]     = (unsigned short)(d & 0xFFFFULL);
                hu.us[e2 * 2 + 1] = (unsigned short)(d >> 32);
            }
#pragma unroll
            for (int g = 0; g < 4; ++g)
                acc[g] = __builtin_amdgcn_mfma_f32_16x16x32_f16(hu.v, wh[g][kk], acc[g], 0, 0, 0);
#pragma unroll
            for (int m = 0; m < 4; ++m)
                hv[kk * 4 + m] = __hip_atomic_load(hpn + kk * 16 + m, __ATOMIC_RELAXED,
                                                   __HIP_MEMORY_SCOPE_AGENT);
        }

        // 5. gates, cell/hidden update, publish tagged h(t)
        const u32 taghi = (u32)t << 16;
        u32* sp = gbase + (size_t)((k * 2 + (t & 1)) * 16 + q * 4) * HD + uglob;
#pragma unroll
        for (int r = 0; r < 4; ++r) {
            const float gp_ = acc[0][r], ip_ = acc[1][r], fp_ = acc[2][r], op_ = acc[3][r];
            const float gg = 1.f - 2.f / (1.f + __expf(2.f * gp_));
            const float ii = 1.f / (1.f + __expf(-ip_));
            const float ff = 1.f / (1.f + __expf(-fp_));
            const float oo = 1.f / (1.f + __expf(-op_));
            c[r] = gg * ii + c[r] * ff;
            const float hh = (1.f - 2.f / (1.f + __expf(2.f * c[r]))) * oo;
            if (t < TSEQ - 1) {
                union { _Float16 f; unsigned short s; } cv;
                cv.f = (_Float16)hh;
                __hip_atomic_store(sp + r * HD, taghi | (u32)cv.s, __ATOMIC_RELAXED,
                                   __HIP_MEMORY_SCOPE_AGENT);
            } else {
                const int b = grp * 32 + k * 16 + q * 4 + r;
                hT[(size_t)b * HD + uglob] = hh;
            }
        }
    };

    for (int t = 1; t < TSEQ; ++t) {
        phase(t, 0, xrow0, xr0, c0);
        phase(t, 1, xrow1, xr1, c1);
    }
}

// ---------------------------------------------------------------------------
// K3: out[b][o] = sum_u hT[b][u] * Wp[o][u] + bp[o]   (fp32)
// ---------------------------------------------------------------------------
__global__ void out_proj(const float* __restrict__ hT, const float* __restrict__ Wp,
                         const float* __restrict__ bp, float* __restrict__ out)
{
    const int b = blockIdx.x;       // 0..255
    const int o = threadIdx.x;      // 0..127
    __shared__ float hrow[HD];
    for (int u = threadIdx.x; u < HD; u += ODIM) hrow[u] = hT[b * HD + u];
    __syncthreads();
    float s = bp[o];
    const float* wr = &Wp[o * HD];
#pragma unroll 8
    for (int u = 0; u < HD; ++u) s += hrow[u] * wr[u];
    out[b * ODIM + o] = s;
}

// ---------------------------------------------------------------------------
extern "C" void kernel_launch(void* const* d_in, const int* in_sizes, int n_in,
                              void* d_out, int out_size, void* d_ws, size_t ws_size,
                              hipStream_t stream) {
    const float* x   = (const float*)d_in[0];
    const float* Wgx = (const float*)d_in[1];
    const float* bgx = (const float*)d_in[2];
    const float* Wgh = (const float*)d_in[3];
    const float* Wix = (const float*)d_in[4];
    const float* bix = (const float*)d_in[5];
    const float* Wih = (const float*)d_in[6];
    const float* Wfx = (const float*)d_in[7];
    const float* bfx = (const float*)d_in[8];
    const float* Wfh = (const float*)d_in[9];
    const float* Wox = (const float*)d_in[10];
    const float* box = (const float*)d_in[11];
    const float* Woh = (const float*)d_in[12];
    const float* Wp  = (const float*)d_in[13];
    const float* bp  = (const float*)d_in[14];
    float* out = (float*)d_out;

    char* ws = (char*)d_ws;
    f16*   Whcat = (f16*)(ws);                         // 1024*256*2        = 524288
    f16*   Wxcat = (f16*)(ws + 524288);                // 1024*128*2        = 262144
    float* bcat  = (float*)(ws + 786432);              // 1024*4            = 4096
    u32*   hbt   = (u32*)(ws + 790528);                // 8*2*2*16*256*4    = 524288
    float* hT    = (float*)(ws + 1314816);             // 256*256*4         = 262144
                                                       // total             = 1576960

    hipMemsetAsync(hbt, 0xFF, 524288, stream);         // tag 0xFFFF = never-valid
    pack_weights<<<1024, 256, 0, stream>>>(Wgh, Wih, Wfh, Woh,
                                           Wgx, Wix, Wfx, Wox,
                                           bgx, bix, bfx, box,
                                           Whcat, Wxcat, bcat);
    lstm_rec<<<32, 256, 0, stream>>>(x, Whcat, Wxcat, bcat, hbt, hT);
    out_proj<<<NBATCH, ODIM, 0, stream>>>(hT, Wp, bp, out);
}

// Round 4
// 5188.757 us; speedup vs baseline: 2.7794x; 2.7794x over previous
//
#include <hip/hip_runtime.h>
#include <hip/hip_fp16.h>

#define TSEQ 1024
#define NBATCH 256
#define HD 256
#define ID 128
#define ODIM 128

typedef _Float16 f16;
typedef _Float16 f16x8 __attribute__((ext_vector_type(8)));
typedef float f32x4 __attribute__((ext_vector_type(4)));
typedef unsigned int u32;
typedef unsigned int u32x4 __attribute__((ext_vector_type(4)));
typedef unsigned long long u64;

// ---- workspace layout (bytes) ----
#define WS_WHCAT 0            // 1024*256*2        = 524288
#define WS_WXCAT 524288       // 1024*128*2        = 262144 (fallback)
#define WS_BCAT  786432       // 1024*4            = 4096   (fallback)
#define WS_BCATG 790528       // 1024*4            = 4096
#define WS_WXG   794624       // 1024*128*2        = 262144
#define WS_HBT   1056768      // 16*2*16*256*4     = 524288
#define WS_HT    1581056      // 256*256*4         = 262144
#define WS_COMM  1843200      // 128*4             = 512
#define WS_FLAGS 1843712      // 256*64*4          = 65536  (fallback)
#define WS_HBUF  1909248      // 2*256*256*2       = 262144 (fallback)
#define WS_GX    2171392      // 256*1024*1024*2   = 536870912
#define WS_NEED  (2171392ULL + 536870912ULL)

#define VMCNT_SB(n) do { asm volatile("s_waitcnt vmcnt(" #n ")" ::: "memory"); \
                         __builtin_amdgcn_sched_barrier(0); } while (0)

// ---------------------------------------------------------------------------
// K0: pack weights. Whcat rows n' = j*256 + g*64 + uu (recurrence B-frags),
// Wxg rows n = u*4+g (xproj GEMM, matches gx[..][u][g] layout), biases both ways.
// ---------------------------------------------------------------------------
__global__ void pack_weights(
    const float* __restrict__ Wgh, const float* __restrict__ Wih,
    const float* __restrict__ Wfh, const float* __restrict__ Woh,
    const float* __restrict__ Wgx, const float* __restrict__ Wix,
    const float* __restrict__ Wfx, const float* __restrict__ Wox,
    const float* __restrict__ bgx, const float* __restrict__ bix,
    const float* __restrict__ bfx, const float* __restrict__ box,
    f16* __restrict__ Whcat, f16* __restrict__ Wxcat, float* __restrict__ bcat,
    float* __restrict__ bcatg, f16* __restrict__ Wxg)
{
    const int np = blockIdx.x;            // 0..1023
    const int g  = (np >> 6) & 3;
    const int j  = np >> 8;
    const int uu = np & 63;
    const int u  = j * 64 + uu;
    const float* Wh = (g == 0) ? Wgh : (g == 1) ? Wih : (g == 2) ? Wfh : Woh;
    const float* Wx = (g == 0) ? Wgx : (g == 1) ? Wix : (g == 2) ? Wfx : Wox;
    const float* bx = (g == 0) ? bgx : (g == 1) ? bix : (g == 2) ? bfx : box;
    const int k = threadIdx.x;            // 0..255
    Whcat[np * 256 + k] = (f16)Wh[u * 256 + k];
    if (k < ID) {
        Wxcat[np * ID + k] = (f16)Wx[u * ID + k];
        Wxg[(size_t)(u * 4 + g) * ID + k] = (f16)Wx[u * ID + k];
    }
    if (k == 0) { bcat[np] = bx[u]; bcatg[u * 4 + g] = bx[u]; }
}

// ---------------------------------------------------------------------------
// K1: gx[b][t][u][g] = bias_g[u] + sum_k x[b][t][k]*Wx_g[u][k]  (fp16 out)
// GEMM: M = B*T (flat rows), N = 1024 (u*4+g), K = 128. WG = 32 rows x 1024 n.
// MFMA 16x16x32 f16: A[m=lane&15][k=q*8+e], B[n=lane&15][k=q*8+e],
//                    D[m=q*4+r][n=lane&15].
// ---------------------------------------------------------------------------
__global__ __launch_bounds__(256, 1) void xproj_gemm(
    const float* __restrict__ x, const f16* __restrict__ Wxg,
    const float* __restrict__ bcatg, f16* __restrict__ gx)
{
    const int tid = threadIdx.x, lane = tid & 63, w = tid >> 6;
    const int q = lane >> 4, n = lane & 15;
    const size_t R0 = (size_t)blockIdx.x * 32;
    const int ncb = w * 256;

    f16x8 a[2][4];
#pragma unroll
    for (int mb = 0; mb < 2; ++mb)
#pragma unroll
        for (int ks = 0; ks < 4; ++ks) {
            const float* xp = &x[(R0 + mb * 16 + n) * ID + ks * 32 + q * 8];
            float4 lo = *(const float4*)xp;
            float4 hi = *(const float4*)(xp + 4);
            f16x8 v;
#pragma unroll
            for (int e = 0; e < 4; ++e) { v[e] = (f16)(&lo.x)[e]; v[4 + e] = (f16)(&hi.x)[e]; }
            a[mb][ks] = v;
        }

    f32x4 acc[2][16];
#pragma unroll
    for (int nb = 0; nb < 16; ++nb) {
        const float bv = bcatg[ncb + nb * 16 + n];
        f32x4 iv = {bv, bv, bv, bv};
        acc[0][nb] = iv; acc[1][nb] = iv;
    }

#pragma unroll 4
    for (int nb = 0; nb < 16; ++nb) {
        const f16* bp = &Wxg[(size_t)(ncb + nb * 16 + n) * ID + q * 8];
        const f16x8 b0 = *(const f16x8*)(bp);
        const f16x8 b1 = *(const f16x8*)(bp + 32);
        const f16x8 b2 = *(const f16x8*)(bp + 64);
        const f16x8 b3 = *(const f16x8*)(bp + 96);
#pragma unroll
        for (int mb = 0; mb < 2; ++mb) {
            acc[mb][nb] = __builtin_amdgcn_mfma_f32_16x16x32_f16(a[mb][0], b0, acc[mb][nb], 0, 0, 0);
            acc[mb][nb] = __builtin_amdgcn_mfma_f32_16x16x32_f16(a[mb][1], b1, acc[mb][nb], 0, 0, 0);
            acc[mb][nb] = __builtin_amdgcn_mfma_f32_16x16x32_f16(a[mb][2], b2, acc[mb][nb], 0, 0, 0);
            acc[mb][nb] = __builtin_amdgcn_mfma_f32_16x16x32_f16(a[mb][3], b3, acc[mb][nb], 0, 0, 0);
        }
    }

#pragma unroll
    for (int mb = 0; mb < 2; ++mb)
#pragma unroll
        for (int nb = 0; nb < 16; ++nb)
#pragma unroll
            for (int r = 0; r < 4; ++r)
                gx[(R0 + mb * 16 + q * 4 + r) * 1024 + (ncb + nb * 16 + n)] =
                    (f16)acc[mb][nb][r];
}

// ---------------------------------------------------------------------------
// Exchange primitives (FAST path). All outputs EARLY-CLOBBER (rounds 2/3 bug).
// ---------------------------------------------------------------------------
__device__ __forceinline__ void hv_issue8_fast(const u32* hp, u32x4 (&hv)[8])
{
    asm volatile(
        "global_load_dwordx4 %0, %8, off sc0\n\t"
        "global_load_dwordx4 %1, %8, off offset:16 sc0\n\t"
        "global_load_dwordx4 %2, %8, off offset:128 sc0\n\t"
        "global_load_dwordx4 %3, %8, off offset:144 sc0\n\t"
        "global_load_dwordx4 %4, %8, off offset:256 sc0\n\t"
        "global_load_dwordx4 %5, %8, off offset:272 sc0\n\t"
        "global_load_dwordx4 %6, %8, off offset:384 sc0\n\t"
        "global_load_dwordx4 %7, %8, off offset:400 sc0"
        : "=&v"(hv[0]), "=&v"(hv[1]), "=&v"(hv[2]), "=&v"(hv[3]),
          "=&v"(hv[4]), "=&v"(hv[5]), "=&v"(hv[6]), "=&v"(hv[7])
        : "v"(hp) : "memory");
}

__device__ __forceinline__ void gx_issue(const f16* g0, const f16* g1,
                                         const f16* g2, const f16* g3, u64 (&gd)[4])
{
    asm volatile(
        "global_load_dwordx2 %0, %4, off\n\t"
        "global_load_dwordx2 %1, %5, off\n\t"
        "global_load_dwordx2 %2, %6, off\n\t"
        "global_load_dwordx2 %3, %7, off"
        : "=&v"(gd[0]), "=&v"(gd[1]), "=&v"(gd[2]), "=&v"(gd[3])
        : "v"(g0), "v"(g1), "v"(g2), "v"(g3) : "memory");
}

__device__ __forceinline__ void h_store4_fast(u32* sp, u32 a, u32 b, u32 c, u32 d)
{
    asm volatile(
        "global_store_dword %4, %0, off sc0\n\t"
        "global_store_dword %4, %1, off offset:1024 sc0\n\t"
        "global_store_dword %4, %2, off offset:2048 sc0\n\t"
        "global_store_dword %4, %3, off offset:3072 sc0"
        :: "v"(a), "v"(b), "v"(c), "v"(d), "v"(sp) : "memory");
}

__device__ __forceinline__ bool tags_ok(const u32x4 (&hv)[8], u32 taghi)
{
    u32 d = 0;
#pragma unroll
    for (int i = 0; i < 8; ++i)
        d |= (hv[i][0] ^ taghi) | (hv[i][1] ^ taghi) | (hv[i][2] ^ taghi) | (hv[i][3] ^ taghi);
    return (d & 0xFFFF0000u) == 0u;
}

__device__ __forceinline__ f16x8 mk_frag(u32x4 a, u32x4 b)
{
    union { unsigned short us[8]; f16x8 v; } u;
#pragma unroll
    for (int e = 0; e < 4; ++e) {
        u.us[e]     = (unsigned short)(a[e] & 0xFFFFu);
        u.us[4 + e] = (unsigned short)(b[e] & 0xFFFFu);
    }
    return u.v;
}

__device__ __forceinline__ void gx_unpack(const u64 (&gd)[4], f32x4 (&acc)[4])
{
    union { u64 u; _Float16 h[4]; } t0, t1, t2, t3;
    t0.u = gd[0]; t1.u = gd[1]; t2.u = gd[2]; t3.u = gd[3];
#pragma unroll
    for (int g = 0; g < 4; ++g) {
        f32x4 a;
        a[0] = (float)t0.h[g]; a[1] = (float)t1.h[g];
        a[2] = (float)t2.h[g]; a[3] = (float)t3.h[g];
        acc[g] = a;
    }
}

// ---------------------------------------------------------------------------
// FAST recurrence body: all loop vmem in asm, counted vmcnt (never drain-0 on
// the happy path), tagged self-validating h over sc0/XCD-L2. Bounded retries.
// ---------------------------------------------------------------------------
__device__ void lstm_fast(const f16* __restrict__ Whcat, const f16* __restrict__ gx,
                          u32* __restrict__ hbt, float* __restrict__ hT,
                          int tid, int grp, int j)
{
    const int lane = tid & 63, w = tid >> 6, q = lane >> 4, n = lane & 15;
    const int b0 = grp * 16;
    const int uglob = j * 64 + w * 16 + n;

    f16x8 wh[4][8];
#pragma unroll
    for (int g = 0; g < 4; ++g) {
        const int row = j * 256 + g * 64 + w * 16 + n;
#pragma unroll
        for (int kk = 0; kk < 8; ++kk)
            wh[g][kk] = *(const f16x8*)&Whcat[row * 256 + kk * 32 + q * 8];
    }

    u32* gbase = hbt + (size_t)grp * (2 * 16 * HD);
    const u32* hp0 = gbase + (size_t)(0 * 16 + n) * HD + q * 8;
    const u32* hp1 = gbase + (size_t)(1 * 16 + n) * HD + q * 8;

    const f16* gp0 = gx + (size_t)(b0 + q * 4 + 0) * TSEQ * 1024 + (size_t)uglob * 4;
    const f16* gp1 = gx + (size_t)(b0 + q * 4 + 1) * TSEQ * 1024 + (size_t)uglob * 4;
    const f16* gp2 = gx + (size_t)(b0 + q * 4 + 2) * TSEQ * 1024 + (size_t)uglob * 4;
    const f16* gp3 = gx + (size_t)(b0 + q * 4 + 3) * TSEQ * 1024 + (size_t)uglob * 4;

    float c[4] = {0.f, 0.f, 0.f, 0.f};
    u64 gxA[4], gxB[4];

    // ---- prologue t = 0 ----
    gx_issue(gp0, gp1, gp2, gp3, gxA);
    gp0 += 1024; gp1 += 1024; gp2 += 1024; gp3 += 1024;
    VMCNT_SB(0);
    {
        f32x4 acc[4];
        gx_unpack(gxA, acc);
        gx_issue(gp0, gp1, gp2, gp3, gxB);                   // gx(1) in flight
        gp0 += 1024; gp1 += 1024; gp2 += 1024; gp3 += 1024;
        u32 hwv[4];
#pragma unroll
        for (int r = 0; r < 4; ++r) {
            const float gp_ = acc[0][r], ip_ = acc[1][r], fp_ = acc[2][r], op_ = acc[3][r];
            const float gg = 1.f - 2.f / (1.f + __expf(2.f * gp_));
            const float ii = 1.f / (1.f + __expf(-ip_));
            const float ff = 1.f / (1.f + __expf(-fp_));
            const float oo = 1.f / (1.f + __expf(-op_));
            c[r] = gg * ii + c[r] * ff;
            const float hh = (1.f - 2.f / (1.f + __expf(2.f * c[r]))) * oo;
            union { _Float16 f; unsigned short s; } cv; cv.f = (_Float16)hh;
            hwv[r] = (u32)cv.s;                               // tag 0
        }
        u32* sp = gbase + (size_t)(0 * 16 + q * 4) * HD + uglob;
        h_store4_fast(sp, hwv[0], hwv[1], hwv[2], hwv[3]);
    }

    // ---- mid step: gU holds gx(t) (4 loads outstanding); issues gx(t+1)->gI ----
    auto stepMid = [&](int t, u64 (&gU)[4], u64 (&gI)[4]) {
        const u32* hp = ((t - 1) & 1) ? hp1 : hp0;
        const u32 taghiP = (u32)(t - 1) << 16;
        u32x4 hv[8];
        hv_issue8_fast(hp, hv);                               // H1: kk 0..3
        gx_issue(gp0, gp1, gp2, gp3, gI);                     // gx(t+1)
        gp0 += 1024; gp1 += 1024; gp2 += 1024; gp3 += 1024;
        VMCNT_SB(12);                                         // gU done (oldest)
        f32x4 acc[4];
        gx_unpack(gU, acc);
        VMCNT_SB(4);                                          // H1 done, gI left
        int tries = 0;
        while (!tags_ok(hv, taghiP)) {
            if (++tries > 16384) break;                       // hang-breaker
            hv_issue8_fast(hp, hv);
            VMCNT_SB(4);
        }
        const f16x8 ha0 = mk_frag(hv[0], hv[1]);
        const f16x8 ha1 = mk_frag(hv[2], hv[3]);
        const f16x8 ha2 = mk_frag(hv[4], hv[5]);
        const f16x8 ha3 = mk_frag(hv[6], hv[7]);
        u32x4 hv2[8];
        hv_issue8_fast(hp + 128, hv2);                        // H2: kk 4..7
#pragma unroll
        for (int g = 0; g < 4; ++g) {
            acc[g] = __builtin_amdgcn_mfma_f32_16x16x32_f16(ha0, wh[g][0], acc[g], 0, 0, 0);
            acc[g] = __builtin_amdgcn_mfma_f32_16x16x32_f16(ha1, wh[g][1], acc[g], 0, 0, 0);
            acc[g] = __builtin_amdgcn_mfma_f32_16x16x32_f16(ha2, wh[g][2], acc[g], 0, 0, 0);
            acc[g] = __builtin_amdgcn_mfma_f32_16x16x32_f16(ha3, wh[g][3], acc[g], 0, 0, 0);
        }
        VMCNT_SB(4);                                          // H2 done, gI left
        tries = 0;
        while (!tags_ok(hv2, taghiP)) {
            if (++tries > 16384) break;
            hv_issue8_fast(hp + 128, hv2);
            VMCNT_SB(4);
        }
        const f16x8 hb0 = mk_frag(hv2[0], hv2[1]);
        const f16x8 hb1 = mk_frag(hv2[2], hv2[3]);
        const f16x8 hb2 = mk_frag(hv2[4], hv2[5]);
        const f16x8 hb3 = mk_frag(hv2[6], hv2[7]);
#pragma unroll
        for (int g = 0; g < 4; ++g) {
            acc[g] = __builtin_amdgcn_mfma_f32_16x16x32_f16(hb0, wh[g][4], acc[g], 0, 0, 0);
            acc[g] = __builtin_amdgcn_mfma_f32_16x16x32_f16(hb1, wh[g][5], acc[g], 0, 0, 0);
            acc[g] = __builtin_amdgcn_mfma_f32_16x16x32_f16(hb2, wh[g][6], acc[g], 0, 0, 0);
            acc[g] = __builtin_amdgcn_mfma_f32_16x16x32_f16(hb3, wh[g][7], acc[g], 0, 0, 0);
        }
        const u32 taghi = (u32)t << 16;
        u32 hwv[4];
#pragma unroll
        for (int r = 0; r < 4; ++r) {
            const float gp_ = acc[0][r], ip_ = acc[1][r], fp_ = acc[2][r], op_ = acc[3][r];
            const float gg = 1.f - 2.f / (1.f + __expf(2.f * gp_));
            const float ii = 1.f / (1.f + __expf(-ip_));
            const float ff = 1.f / (1.f + __expf(-fp_));
            const float oo = 1.f / (1.f + __expf(-op_));
            c[r] = gg * ii + c[r] * ff;
            const float hh = (1.f - 2.f / (1.f + __expf(2.f * c[r]))) * oo;
            union { _Float16 f; unsigned short s; } cv; cv.f = (_Float16)hh;
            hwv[r] = taghi | (u32)cv.s;
        }
        u32* sp = gbase + (size_t)(((t & 1) * 16 + q * 4)) * HD + uglob;
        h_store4_fast(sp, hwv[0], hwv[1], hwv[2], hwv[3]);
    };

    for (int t = 1; t <= 1021; t += 2) {
        stepMid(t,     gxB, gxA);
        stepMid(t + 1, gxA, gxB);
    }

    // ---- final step t = 1023 (uses gxB; no prefetch; hT stores) ----
    {
        const int t = 1023;
        const u32* hp = hp0;                                  // (t-1)=1022, parity 0
        const u32 taghiP = (u32)(t - 1) << 16;
        u32x4 hv[8];
        hv_issue8_fast(hp, hv);
        VMCNT_SB(8);                                          // gxB done, H1 left
        f32x4 acc[4];
        gx_unpack(gxB, acc);
        VMCNT_SB(0);
        int tries = 0;
        while (!tags_ok(hv, taghiP)) {
            if (++tries > 16384) break;
            hv_issue8_fast(hp, hv);
            VMCNT_SB(0);
        }
        const f16x8 ha0 = mk_frag(hv[0], hv[1]);
        const f16x8 ha1 = mk_frag(hv[2], hv[3]);
        const f16x8 ha2 = mk_frag(hv[4], hv[5]);
        const f16x8 ha3 = mk_frag(hv[6], hv[7]);
        u32x4 hv2[8];
        hv_issue8_fast(hp + 128, hv2);
#pragma unroll
        for (int g = 0; g < 4; ++g) {
            acc[g] = __builtin_amdgcn_mfma_f32_16x16x32_f16(ha0, wh[g][0], acc[g], 0, 0, 0);
            acc[g] = __builtin_amdgcn_mfma_f32_16x16x32_f16(ha1, wh[g][1], acc[g], 0, 0, 0);
            acc[g] = __builtin_amdgcn_mfma_f32_16x16x32_f16(ha2, wh[g][2], acc[g], 0, 0, 0);
            acc[g] = __builtin_amdgcn_mfma_f32_16x16x32_f16(ha3, wh[g][3], acc[g], 0, 0, 0);
        }
        VMCNT_SB(0);
        tries = 0;
        while (!tags_ok(hv2, taghiP)) {
            if (++tries > 16384) break;
            hv_issue8_fast(hp + 128, hv2);
            VMCNT_SB(0);
        }
        const f16x8 hb0 = mk_frag(hv2[0], hv2[1]);
        const f16x8 hb1 = mk_frag(hv2[2], hv2[3]);
        const f16x8 hb2 = mk_frag(hv2[4], hv2[5]);
        const f16x8 hb3 = mk_frag(hv2[6], hv2[7]);
#pragma unroll
        for (int g = 0; g < 4; ++g) {
            acc[g] = __builtin_amdgcn_mfma_f32_16x16x32_f16(hb0, wh[g][4], acc[g], 0, 0, 0);
            acc[g] = __builtin_amdgcn_mfma_f32_16x16x32_f16(hb1, wh[g][5], acc[g], 0, 0, 0);
            acc[g] = __builtin_amdgcn_mfma_f32_16x16x32_f16(hb2, wh[g][6], acc[g], 0, 0, 0);
            acc[g] = __builtin_amdgcn_mfma_f32_16x16x32_f16(hb3, wh[g][7], acc[g], 0, 0, 0);
        }
#pragma unroll
        for (int r = 0; r < 4; ++r) {
            const float gp_ = acc[0][r], ip_ = acc[1][r], fp_ = acc[2][r], op_ = acc[3][r];
            const float gg = 1.f - 2.f / (1.f + __expf(2.f * gp_));
            const float ii = 1.f / (1.f + __expf(-ip_));
            const float ff = 1.f / (1.f + __expf(-fp_));
            const float oo = 1.f / (1.f + __expf(-op_));
            c[r] = gg * ii + c[r] * ff;
            const float hh = (1.f - 2.f / (1.f + __expf(2.f * c[r]))) * oo;
            hT[(size_t)(b0 + q * 4 + r) * HD + uglob] = hh;
        }
    }
}

// ---------------------------------------------------------------------------
// SLOW body: same protocol over round-0/1-proven agent-scope intrinsics.
// ---------------------------------------------------------------------------
__device__ void lstm_slow(const f16* __restrict__ Whcat, const f16* __restrict__ gx,
                          u32* __restrict__ hbt, float* __restrict__ hT,
                          int tid, int grp, int j)
{
    const int lane = tid & 63, w = tid >> 6, q = lane >> 4, n = lane & 15;
    const int b0 = grp * 16;
    const int uglob = j * 64 + w * 16 + n;

    f16x8 wh[4][8];
#pragma unroll
    for (int g = 0; g < 4; ++g) {
        const int row = j * 256 + g * 64 + w * 16 + n;
#pragma unroll
        for (int kk = 0; kk < 8; ++kk)
            wh[g][kk] = *(const f16x8*)&Whcat[row * 256 + kk * 32 + q * 8];
    }

    u32* gbase = hbt + (size_t)grp * (2 * 16 * HD);
    const f16* gpr[1]; (void)gpr;
    const f16* gpb0 = gx + (size_t)(b0 + q * 4 + 0) * TSEQ * 1024 + (size_t)uglob * 4;
    const f16* gpb1 = gx + (size_t)(b0 + q * 4 + 1) * TSEQ * 1024 + (size_t)uglob * 4;
    const f16* gpb2 = gx + (size_t)(b0 + q * 4 + 2) * TSEQ * 1024 + (size_t)uglob * 4;
    const f16* gpb3 = gx + (size_t)(b0 + q * 4 + 3) * TSEQ * 1024 + (size_t)uglob * 4;
    float c[4] = {0.f, 0.f, 0.f, 0.f};

    for (int t = 0; t < TSEQ; ++t) {
        u64 gd[4];
        gd[0] = *(const u64*)gpb0; gd[1] = *(const u64*)gpb1;
        gd[2] = *(const u64*)gpb2; gd[3] = *(const u64*)gpb3;
        gpb0 += 1024; gpb1 += 1024; gpb2 += 1024; gpb3 += 1024;
        f32x4 acc[4];
        gx_unpack(gd, acc);

        if (t > 0) {
            const int pp = (t - 1) & 1;
            const u32* hp = gbase + (size_t)(pp * 16 + n) * HD + q * 8;
            const u32 taghiP = (u32)(t - 1) << 16;
            u32 hvw[64];
            int tries = 0;
            for (;;) {
#pragma unroll
                for (int kk = 0; kk < 8; ++kk)
#pragma unroll
                    for (int e = 0; e < 8; ++e)
                        hvw[kk * 8 + e] = __hip_atomic_load(hp + kk * 32 + e,
                                            __ATOMIC_RELAXED, __HIP_MEMORY_SCOPE_AGENT);
                u32 d = 0;
#pragma unroll
                for (int i = 0; i < 64; ++i) d |= hvw[i] ^ taghiP;
                if ((d & 0xFFFF0000u) == 0u) break;
                if (++tries > 16384) break;
                __builtin_amdgcn_s_sleep(2);
            }
#pragma unroll
            for (int kk = 0; kk < 8; ++kk) {
                union { unsigned short us[8]; f16x8 v; } hu;
#pragma unroll
                for (int e = 0; e < 8; ++e)
                    hu.us[e] = (unsigned short)(hvw[kk * 8 + e] & 0xFFFFu);
#pragma unroll
                for (int g = 0; g < 4; ++g)
                    acc[g] = __builtin_amdgcn_mfma_f32_16x16x32_f16(hu.v, wh[g][kk], acc[g], 0, 0, 0);
            }
        }

        const u32 taghi = (u32)t << 16;
        u32* sp = gbase + (size_t)(((t & 1) * 16 + q * 4)) * HD + uglob;
#pragma unroll
        for (int r = 0; r < 4; ++r) {
            const float gp_ = acc[0][r], ip_ = acc[1][r], fp_ = acc[2][r], op_ = acc[3][r];
            const float gg = 1.f - 2.f / (1.f + __expf(2.f * gp_));
            const float ii = 1.f / (1.f + __expf(-ip_));
            const float ff = 1.f / (1.f + __expf(-fp_));
            const float oo = 1.f / (1.f + __expf(-op_));
            c[r] = gg * ii + c[r] * ff;
            const float hh = (1.f - 2.f / (1.f + __expf(2.f * c[r]))) * oo;
            if (t < TSEQ - 1) {
                union { _Float16 f; unsigned short s; } cv; cv.f = (_Float16)hh;
                __hip_atomic_store(sp + r * HD, taghi | (u32)cv.s,
                                   __ATOMIC_RELAXED, __HIP_MEMORY_SCOPE_AGENT);
            } else {
                hT[(size_t)(b0 + q * 4 + r) * HD + uglob] = hh;
            }
        }
    }
}

// ---------------------------------------------------------------------------
// K2: probe sc0/L2 reachability of the 4 group members, then branch.
// Group members: bids {half*32 + m*8 + xcd} (same residue mod 8 -> same XCD
// under round-robin dispatch; VERIFIED by the probe, never assumed).
// ---------------------------------------------------------------------------
__global__ __launch_bounds__(256, 1) void lstm_rec(
    const f16* __restrict__ Whcat, const f16* __restrict__ gx,
    u32* __restrict__ hbt, float* __restrict__ hT, u32* __restrict__ comm)
{
    const int tid  = threadIdx.x;
    const int bid  = blockIdx.x;
    const int xcd  = bid & 7;
    const int j    = (bid >> 3) & 3;
    const int half = bid >> 5;
    const int grp  = xcd * 2 + half;

    __shared__ int s_fast;
    if (tid == 0) {
        u32* probe = comm;          // [64], memset 0 each launch
        u32* flg   = comm + 64;     // [64], memset 0 each launch
        const u32 salt = 0xA5C30000u;
        {
            const u32 v = salt | (u32)bid;
            asm volatile("global_store_dword %0, %1, off sc0\n\ts_waitcnt vmcnt(0)"
                         :: "v"(&probe[bid]), "v"(v) : "memory");
        }
        const int need = 0xF ^ (1 << j);
        int seen = 0;
        for (int it = 0; it < 2048 && seen != need; ++it) {
#pragma unroll
            for (int m = 0; m < 4; ++m) {
                if (m == j || (seen & (1 << m))) continue;
                const int pb = half * 32 + m * 8 + xcd;
                u32 v;
                asm volatile("global_load_dword %0, %1, off sc0\n\ts_waitcnt vmcnt(0)"
                             : "=&v"(v) : "v"(&probe[pb]) : "memory");
                if (v == (salt | (u32)pb)) seen |= (1 << m);
            }
        }
        const u32 ok = (seen == need) ? 2u : 1u;
        __hip_atomic_store(&flg[bid], ok, __ATOMIC_RELAXED, __HIP_MEMORY_SCOPE_AGENT);
        int allok = (ok == 2u);
        for (int m = 0; m < 4; ++m) {
            if (m == j) continue;
            const int pb = half * 32 + m * 8 + xcd;
            u32 v = 0; int it2 = 0;
            do {
                v = __hip_atomic_load(&flg[pb], __ATOMIC_RELAXED, __HIP_MEMORY_SCOPE_AGENT);
            } while (v == 0u && ++it2 < (1 << 20));
            allok &= (v == 2u);
        }
        s_fast = allok;
    }
    __syncthreads();

    if (s_fast) lstm_fast(Whcat, gx, hbt, hT, tid, grp, j);
    else        lstm_slow(Whcat, gx, hbt, hT, tid, grp, j);
}

// ---------------------------------------------------------------------------
// Fallback: verbatim round-0 kernel (measured 5.15 ms, passing) — used only
// if ws_size cannot hold gx.
// ---------------------------------------------------------------------------
__global__ __launch_bounds__(256, 1) void lstm_rec_fb(
    const float* __restrict__ x,
    const f16* __restrict__ Whcat,
    const f16* __restrict__ Wxcat,
    const float* __restrict__ bcat,
    f16* __restrict__ hbuf, float* __restrict__ hT, int* __restrict__ flags)
{
    const int tid  = threadIdx.x;
    const int lane = tid & 63;
    const int w    = tid >> 6;
    const int q    = lane >> 4;
    const int n    = lane & 15;
    const int bid  = blockIdx.x;
    const int grp  = bid >> 2;
    const int j    = bid & 3;
    const int b0   = grp * 16;

    f16x8 wh[4][8];
    f16x8 wx[4][4];
    float bias[4];
#pragma unroll
    for (int g = 0; g < 4; ++g) {
        const int row = j * 256 + g * 64 + w * 16 + n;
        bias[g] = bcat[row];
#pragma unroll
        for (int kk = 0; kk < 8; ++kk)
            wh[g][kk] = *(const f16x8*)&Whcat[row * 256 + kk * 32 + q * 8];
#pragma unroll
        for (int k4 = 0; k4 < 4; ++k4)
            wx[g][k4] = *(const f16x8*)&Wxcat[row * ID + k4 * 32 + q * 8];
    }

    float c[4] = {0.f, 0.f, 0.f, 0.f};
    const int uglob    = j * 64 + w * 16 + n;
    const int myslot   = (grp * 16 + j * 4 + w) * 64;
    const int pollslot = (grp * 16 + tid) * 64;

    const float* xrow = &x[(size_t)(b0 + n) * TSEQ * ID];
    float4 xr[8];
#pragma unroll
    for (int k4 = 0; k4 < 4; ++k4) {
        xr[k4 * 2]     = *(const float4*)&xrow[k4 * 32 + q * 8];
        xr[k4 * 2 + 1] = *(const float4*)&xrow[k4 * 32 + q * 8 + 4];
    }

    for (int t = 0; t < TSEQ; ++t) {
        f16x8 xa[4];
#pragma unroll
        for (int k4 = 0; k4 < 4; ++k4) {
            const float* f0 = (const float*)&xr[k4 * 2];
            const float* f1 = (const float*)&xr[k4 * 2 + 1];
#pragma unroll
            for (int e = 0; e < 4; ++e) {
                xa[k4][e]     = (f16)f0[e];
                xa[k4][4 + e] = (f16)f1[e];
            }
        }
        if (t + 1 < TSEQ) {
            const float* xp = &xrow[(size_t)(t + 1) * ID];
#pragma unroll
            for (int k4 = 0; k4 < 4; ++k4) {
                xr[k4 * 2]     = *(const float4*)&xp[k4 * 32 + q * 8];
                xr[k4 * 2 + 1] = *(const float4*)&xp[k4 * 32 + q * 8 + 4];
            }
        }

        f32x4 acc[4];
#pragma unroll
        for (int g = 0; g < 4; ++g) { f32x4 av = {bias[g], bias[g], bias[g], bias[g]}; acc[g] = av; }
#pragma unroll
        for (int k4 = 0; k4 < 4; ++k4)
#pragma unroll
            for (int g = 0; g < 4; ++g)
                acc[g] = __builtin_amdgcn_mfma_f32_16x16x32_f16(xa[k4], wx[g][k4], acc[g], 0, 0, 0);

        if (t > 0) {
            if (tid < 16) {
                while (__hip_atomic_load(&flags[pollslot], __ATOMIC_RELAXED,
                                         __HIP_MEMORY_SCOPE_AGENT) < t)
                    __builtin_amdgcn_s_sleep(1);
            }
            __syncthreads();
            const unsigned long long* hp = (const unsigned long long*)
                &hbuf[(size_t)(((t - 1) & 1) * NBATCH + b0 + n) * HD];
            f16x8 ha[8];
#pragma unroll
            for (int kk = 0; kk < 8; ++kk) {
                union { unsigned long long u[2]; f16x8 v; } hu;
                hu.u[0] = __hip_atomic_load(hp + kk * 8 + q * 2,     __ATOMIC_RELAXED,
                                            __HIP_MEMORY_SCOPE_AGENT);
                hu.u[1] = __hip_atomic_load(hp + kk * 8 + q * 2 + 1, __ATOMIC_RELAXED,
                                            __HIP_MEMORY_SCOPE_AGENT);
                ha[kk] = hu.v;
            }
#pragma unroll
            for (int kk = 0; kk < 8; ++kk)
#pragma unroll
                for (int g = 0; g < 4; ++g)
                    acc[g] = __builtin_amdgcn_mfma_f32_16x16x32_f16(ha[kk], wh[g][kk], acc[g], 0, 0, 0);
        }

#pragma unroll
        for (int r = 0; r < 4; ++r) {
            const float gp_ = acc[0][r], ip_ = acc[1][r], fp_ = acc[2][r], op_ = acc[3][r];
            const float gg = 1.f - 2.f / (1.f + __expf(2.f * gp_));
            const float ii = 1.f / (1.f + __expf(-ip_));
            const float ff = 1.f / (1.f + __expf(-fp_));
            const float oo = 1.f / (1.f + __expf(-op_));
            c[r] = gg * ii + c[r] * ff;
            const float hh = (1.f - 2.f / (1.f + __expf(2.f * c[r]))) * oo;
            const int b = b0 + q * 4 + r;
            if (t < TSEQ - 1) {
                union { _Float16 f; unsigned short s; } cv;
                cv.f = (_Float16)hh;
                __hip_atomic_store((unsigned short*)&hbuf[(size_t)((t & 1) * NBATCH + b) * HD + uglob],
                                   cv.s, __ATOMIC_RELAXED, __HIP_MEMORY_SCOPE_AGENT);
            } else {
                hT[(size_t)b * HD + uglob] = hh;
            }
        }

        if (t < TSEQ - 1) {
            __atomic_signal_fence(__ATOMIC_SEQ_CST);
            __builtin_amdgcn_s_waitcnt(0x0F70);
            __atomic_signal_fence(__ATOMIC_SEQ_CST);
            if (lane == 0)
                __hip_atomic_store(&flags[myslot], t + 1, __ATOMIC_RELAXED,
                                   __HIP_MEMORY_SCOPE_AGENT);
        }
    }
}

// ---------------------------------------------------------------------------
// K3: out[b][o] = sum_u hT[b][u] * Wp[o][u] + bp[o]
// ---------------------------------------------------------------------------
__global__ void out_proj(const float* __restrict__ hT, const float* __restrict__ Wp,
                         const float* __restrict__ bp, float* __restrict__ out)
{
    const int b = blockIdx.x;
    const int o = threadIdx.x;
    __shared__ float hrow[HD];
    for (int u = threadIdx.x; u < HD; u += ODIM) hrow[u] = hT[b * HD + u];
    __syncthreads();
    float s = bp[o];
    const float* wr = &Wp[o * HD];
#pragma unroll 8
    for (int u = 0; u < HD; ++u) s += hrow[u] * wr[u];
    out[b * ODIM + o] = s;
}

// ---------------------------------------------------------------------------
extern "C" void kernel_launch(void* const* d_in, const int* in_sizes, int n_in,
                              void* d_out, int out_size, void* d_ws, size_t ws_size,
                              hipStream_t stream) {
    const float* x   = (const float*)d_in[0];
    const float* Wgx = (const float*)d_in[1];
    const float* bgx = (const float*)d_in[2];
    const float* Wgh = (const float*)d_in[3];
    const float* Wix = (const float*)d_in[4];
    const float* bix = (const float*)d_in[5];
    const float* Wih = (const float*)d_in[6];
    const float* Wfx = (const float*)d_in[7];
    const float* bfx = (const float*)d_in[8];
    const float* Wfh = (const float*)d_in[9];
    const float* Wox = (const float*)d_in[10];
    const float* box = (const float*)d_in[11];
    const float* Woh = (const float*)d_in[12];
    const float* Wp  = (const float*)d_in[13];
    const float* bp  = (const float*)d_in[14];
    float* out = (float*)d_out;

    char* ws = (char*)d_ws;
    f16*   Whcat = (f16*)(ws + WS_WHCAT);
    f16*   Wxcat = (f16*)(ws + WS_WXCAT);
    float* bcat  = (float*)(ws + WS_BCAT);
    float* bcatg = (float*)(ws + WS_BCATG);
    f16*   Wxg   = (f16*)(ws + WS_WXG);
    u32*   hbt   = (u32*)(ws + WS_HBT);
    float* hT    = (float*)(ws + WS_HT);
    u32*   comm  = (u32*)(ws + WS_COMM);
    int*   flags = (int*)(ws + WS_FLAGS);
    f16*   hbuf  = (f16*)(ws + WS_HBUF);
    f16*   gxbuf = (f16*)(ws + WS_GX);

    hipMemsetAsync(hbt, 0xFF, 524288, stream);     // tag 0xFFFF never valid
    hipMemsetAsync(comm, 0, 512, stream);
    hipMemsetAsync(flags, 0, 65536, stream);

    pack_weights<<<1024, 256, 0, stream>>>(Wgh, Wih, Wfh, Woh,
                                           Wgx, Wix, Wfx, Wox,
                                           bgx, bix, bfx, box,
                                           Whcat, Wxcat, bcat, bcatg, Wxg);

    if (ws_size >= WS_NEED) {
        xproj_gemm<<<8192, 256, 0, stream>>>(x, Wxg, bcatg, gxbuf);
        lstm_rec<<<64, 256, 0, stream>>>(Whcat, gxbuf, hbt, hT, comm);
    } else {
        lstm_rec_fb<<<64, 256, 0, stream>>>(x, Whcat, Wxcat, bcat, hbuf, hT, flags);
    }
    out_proj<<<NBATCH, ODIM, 0, stream>>>(hT, Wp, bp, out);
}